// Round 13
// baseline (109.397 us; speedup 1.0000x reference)
//
#include <hip/hip_runtime.h>
#include <hip/hip_bf16.h>
#include <math.h>

#define BB    2
#define NN    20000
#define FF    128
#define EE    640000
#define EP    (EE + NN)      // edges + self loops = 660000
#define CAPR  64             // per-replica bucket capacity (Poisson(8.25): P(>=64)~e^-78)
#define SLOPE 0.2f

typedef __attribute__((ext_vector_type(8))) short bf16x8;
typedef __attribute__((ext_vector_type(4))) float f32x4;
typedef __attribute__((ext_vector_type(2))) float f32x2;

static __device__ __forceinline__ ushort f2bf(float f) {
    unsigned u = __float_as_uint(f);
    u += 0x7fffu + ((u >> 16) & 1u);     // round-to-nearest-even
    return (ushort)(u >> 16);
}
static __device__ __forceinline__ float bflo(unsigned q) {
    return __uint_as_float(q << 16);
}
static __device__ __forceinline__ float bfhi(unsigned q) {
    return __uint_as_float(q & 0xffff0000u);
}

// ---------------------------------------------------------------------------
// MFMA GEMM: h = bf16(x) @ bf16(W)^T, f32 accumulate. Zeroes cnt4[].
// h stored batch-interleaved: hbu[n*128 + pair*2 + b] = bf16x2(h[b][n][2p..2p+1])
// Block: 256 thr (4 waves), tile 64 rows x 128 cols, K=128.
// LDS tiles XOR-swizzled (byte ^= (row&7)<<4) -> conflict-free ds_read_b128.
// ---------------------------------------------------------------------------
__global__ __launch_bounds__(256) void gemm_att_kernel(
    const float* __restrict__ x, const float* __restrict__ W,
    const float* __restrict__ att_src, const float* __restrict__ att_dst,
    unsigned* __restrict__ hbu, float* __restrict__ as2, float* __restrict__ ad2,
    int* __restrict__ cnt4)
{
    __shared__ ushort XL[64 * 128];    // 16 KB swizzled bf16 x-tile
    __shared__ ushort WL[128 * 128];   // 32 KB swizzled bf16 W (row c, col k)
    const int tid = threadIdx.x;
    const int r0 = blockIdx.x * 64;

    // zero replicated bucket counters (gemm completes before scatter launches)
    if (blockIdx.x < 313) {
        int i = blockIdx.x * 256 + tid;
        if (i < 4 * NN) cnt4[i] = 0;
    }

    // stage x tile: 64 rows x 128 f32 = 2048 float4
    {
        const float4* xg = (const float4*)(x + (size_t)r0 * 128);
        #pragma unroll
        for (int i = 0; i < 8; ++i) {
            int idx = tid + i * 256;          // float4 idx; 32 per row
            int r = idx >> 5, k = (idx & 31) * 4;
            float4 v = xg[idx];
            ushort4 p = { f2bf(v.x), f2bf(v.y), f2bf(v.z), f2bf(v.w) };
            unsigned byte = ((unsigned)r << 8) + ((unsigned)k << 1);
            byte ^= (unsigned)(r & 7) << 4;
            *(ushort4*)((char*)XL + byte) = p;
        }
    }
    // stage W: 128x128 f32 = 4096 float4
    {
        const float4* wg = (const float4*)W;
        #pragma unroll
        for (int i = 0; i < 16; ++i) {
            int idx = tid + i * 256;
            int c = idx >> 5, k = (idx & 31) * 4;
            float4 v = wg[idx];
            ushort4 p = { f2bf(v.x), f2bf(v.y), f2bf(v.z), f2bf(v.w) };
            unsigned byte = ((unsigned)c << 8) + ((unsigned)k << 1);
            byte ^= (unsigned)(c & 7) << 4;
            *(ushort4*)((char*)WL + byte) = p;
        }
    }
    __syncthreads();

    const int wid = tid >> 6, lane = tid & 63;
    const int l15 = lane & 15, lg = lane >> 4;
    f32x4 acc[8];
    #pragma unroll
    for (int i = 0; i < 8; ++i) acc[i] = (f32x4){0.f, 0.f, 0.f, 0.f};

    const int arow = wid * 16 + l15;
    #pragma unroll
    for (int kt = 0; kt < 4; ++kt) {
        unsigned abyte = ((unsigned)arow << 8) + (unsigned)(kt * 64 + lg * 16);
        abyte ^= (unsigned)(arow & 7) << 4;
        bf16x8 af = *(const bf16x8*)((const char*)XL + abyte);
        #pragma unroll
        for (int ct = 0; ct < 8; ++ct) {
            int c = ct * 16 + l15;
            unsigned bbyte = ((unsigned)c << 8) + (unsigned)(kt * 64 + lg * 16);
            bbyte ^= (unsigned)(c & 7) << 4;
            bf16x8 bfr = *(const bf16x8*)((const char*)WL + bbyte);
            acc[ct] = __builtin_amdgcn_mfma_f32_16x16x32_bf16(af, bfr, acc[ct], 0, 0, 0);
        }
    }

    // a_src/a_dst from f32 accumulators: row = wid*16 + lg*4 + reg, col = ct*16+l15
    float ps0=0,ps1=0,ps2=0,ps3=0, pd0=0,pd1=0,pd2=0,pd3=0;
    #pragma unroll
    for (int ct = 0; ct < 8; ++ct) {
        int c = ct * 16 + l15;
        float as_ = att_src[c], ad_ = att_dst[c];
        ps0 += acc[ct][0]*as_; pd0 += acc[ct][0]*ad_;
        ps1 += acc[ct][1]*as_; pd1 += acc[ct][1]*ad_;
        ps2 += acc[ct][2]*as_; pd2 += acc[ct][2]*ad_;
        ps3 += acc[ct][3]*as_; pd3 += acc[ct][3]*ad_;
    }
    #pragma unroll
    for (int o = 1; o < 16; o <<= 1) {
        ps0 += __shfl_xor(ps0, o, 64); pd0 += __shfl_xor(pd0, o, 64);
        ps1 += __shfl_xor(ps1, o, 64); pd1 += __shfl_xor(pd1, o, 64);
        ps2 += __shfl_xor(ps2, o, 64); pd2 += __shfl_xor(pd2, o, 64);
        ps3 += __shfl_xor(ps3, o, 64); pd3 += __shfl_xor(pd3, o, 64);
    }
    if (l15 == 0) {
        int rb = r0 + wid * 16 + lg * 4;     // multiple of 4; quads never cross NN
        #pragma unroll
        for (int q = 0; q < 4; ++q) {
            int r = rb + q;
            int b = (r >= NN);
            int n = r - b * NN;
            float ps = q==0?ps0 : q==1?ps1 : q==2?ps2 : ps3;
            float pd = q==0?pd0 : q==1?pd1 : q==2?pd2 : pd3;
            as2[n * 2 + b] = ps;             // batch-packed float2 halves
            ad2[n * 2 + b] = pd;
        }
    }

    // h epilogue: acc -> LDS bf16 (linear) -> batch-interleaved global write
    __syncthreads();
    ushort* hl = (ushort*)WL;          // reuse 16 KB of WL
    {
        int rb = wid * 16 + lg * 4;
        #pragma unroll
        for (int ct = 0; ct < 8; ++ct) {
            int c = ct * 16 + l15;
            hl[(rb+0) * 128 + c] = f2bf(acc[ct][0]);
            hl[(rb+1) * 128 + c] = f2bf(acc[ct][1]);
            hl[(rb+2) * 128 + c] = f2bf(acc[ct][2]);
            hl[(rb+3) * 128 + c] = f2bf(acc[ct][3]);
        }
    }
    __syncthreads();
    {
        const unsigned* hs = (const unsigned*)hl;   // 64 rows x 64 pairs
        #pragma unroll
        for (int i = 0; i < 16; ++i) {
            int idx = tid + i * 256;       // 0..4095
            int row = idx >> 6, p = idx & 63;
            int r = r0 + row;
            int b = (r >= NN);
            int n = r - b * NN;
            hbu[(size_t)n * 128 + p * 2 + b] = hs[row * 64 + p];
        }
    }
}

// ---------------------------------------------------------------------------
// Scatter: minimal per-edge work. Replica r = e&3 cuts same-address atomic
// serialization 4x; 2-B nontemporal record store (no L2 write-allocate).
// 4 edges per thread (grid-stride) for ILP.
// ---------------------------------------------------------------------------
__global__ __launch_bounds__(256) void scatter_kernel(
    const int* __restrict__ ei, int* __restrict__ cnt4, ushort* __restrict__ buck)
{
    const int base = blockIdx.x * 1024 + threadIdx.x;
    #pragma unroll
    for (int k = 0; k < 4; ++k) {
        int e = base + k * 256;
        if (e >= EP) continue;
        int s, d;
        if (e < EE) {
            s = __builtin_nontemporal_load(ei + e);
            d = __builtin_nontemporal_load(ei + EE + e);
            if ((unsigned)s >= NN || (unsigned)d >= NN) continue;
        } else {
            s = d = e - EE;
        }
        int r = e & 3;
        int slot = atomicAdd(&cnt4[r * NN + d], 1);
        if (slot < CAPR) {
            ushort v = (ushort)s;
            __builtin_nontemporal_store(v, &buck[(((size_t)r * NN + d) << 6) + slot]);
        }
    }
}

// ---------------------------------------------------------------------------
// Gather: ONE WAVE per node (4 nodes per 256-thr block). No __syncthreads.
// Stage: 4 coalesced sub-segment reads (one per replica); per-edge weights
// computed here from one random 8-B as2[s] load (f32 exp); den via shuffle.
// Inner loop: unroll x4 -> 4 h-loads (512 B each) in flight per wave.
// ---------------------------------------------------------------------------
__global__ __launch_bounds__(256) void gather_kernel(
    const uint2* __restrict__ h,             // [N][64] uint2 {b0 pair, b1 pair}
    const int* __restrict__ cnt4, const ushort* __restrict__ buck,
    const float2* __restrict__ as2, const float2* __restrict__ ad2,
    const float* __restrict__ bias, float* __restrict__ out)
{
    const int tid = threadIdx.x;
    const int wid = tid >> 6, lane = tid & 63;
    const int n = blockIdx.x * 4 + wid;

    __shared__ ushort ssrc[4][128];
    __shared__ float2 swp[4][128];

    const float2 adv = ad2[n];
    int c0 = min(cnt4[0 * NN + n], CAPR);
    int c1 = min(cnt4[1 * NN + n], CAPR);
    int c2 = min(cnt4[2 * NN + n], CAPR);
    int c3 = min(cnt4[3 * NN + n], CAPR);
    const int b1 = c0, b2 = c0 + c1, b3 = c0 + c1 + c2;
    const int cn = min(b3 + c3, 128);

    float den0 = 0.f, den1 = 0.f;
    #pragma unroll
    for (int r = 0; r < 4; ++r) {
        int cr = r==0?c0 : r==1?c1 : r==2?c2 : c3;
        int br = r==0?0  : r==1?b1 : r==2?b2 : b3;
        if (lane < cr) {
            int idx = br + lane;
            ushort s = __builtin_nontemporal_load(
                &buck[(((size_t)r * NN + n) << 6) + lane]);
            float2 asv = as2[s];
            float l0 = asv.x + adv.x; l0 = l0 > 0.f ? l0 : SLOPE * l0;
            float l1 = asv.y + adv.y; l1 = l1 > 0.f ? l1 : SLOPE * l1;
            float w0 = __expf(l0), w1 = __expf(l1);
            if (idx < 128) {
                ssrc[wid][idx] = s;
                swp[wid][idx] = (float2){w0, w1};
                den0 += w0; den1 += w1;
            }
        }
    }
    #pragma unroll
    for (int o = 32; o > 0; o >>= 1) {
        den0 += __shfl_xor(den0, o, 64);
        den1 += __shfl_xor(den1, o, 64);
    }

    float a0x = 0.f, a0y = 0.f, a1x = 0.f, a1y = 0.f;
    int j = 0;
    for (; j + 3 < cn; j += 4) {
        int s0 = ssrc[wid][j],     s1 = ssrc[wid][j + 1];
        int s2 = ssrc[wid][j + 2], s3 = ssrc[wid][j + 3];
        uint2 q0 = h[(size_t)s0 * 64 + lane];
        uint2 q1 = h[(size_t)s1 * 64 + lane];
        uint2 q2 = h[(size_t)s2 * 64 + lane];
        uint2 q3 = h[(size_t)s3 * 64 + lane];
        float2 w0 = swp[wid][j],     w1 = swp[wid][j + 1];
        float2 w2 = swp[wid][j + 2], w3 = swp[wid][j + 3];
        a0x += w0.x * bflo(q0.x); a0y += w0.x * bfhi(q0.x);
        a1x += w0.y * bflo(q0.y); a1y += w0.y * bfhi(q0.y);
        a0x += w1.x * bflo(q1.x); a0y += w1.x * bfhi(q1.x);
        a1x += w1.y * bflo(q1.y); a1y += w1.y * bfhi(q1.y);
        a0x += w2.x * bflo(q2.x); a0y += w2.x * bfhi(q2.x);
        a1x += w2.y * bflo(q2.y); a1y += w2.y * bfhi(q2.y);
        a0x += w3.x * bflo(q3.x); a0y += w3.x * bfhi(q3.x);
        a1x += w3.y * bflo(q3.y); a1y += w3.y * bfhi(q3.y);
    }
    for (; j < cn; ++j) {
        int s0 = ssrc[wid][j];
        uint2 q0 = h[(size_t)s0 * 64 + lane];
        float2 w0 = swp[wid][j];
        a0x += w0.x * bflo(q0.x); a0y += w0.x * bfhi(q0.x);
        a1x += w0.y * bflo(q0.y); a1y += w0.y * bfhi(q0.y);
    }

    float r0 = 1.f / den0, r1 = 1.f / den1;
    float2 bv = *(const float2*)&bias[lane * 2];
    f32x2 o0 = { a0x * r0 + bv.x, a0y * r0 + bv.y };
    f32x2 o1 = { a1x * r1 + bv.x, a1y * r1 + bv.y };
    f32x2* op0 = (f32x2*)&out[(size_t)n * 128 + lane * 2];
    f32x2* op1 = (f32x2*)&out[((size_t)NN + n) * 128 + lane * 2];
    __builtin_nontemporal_store(o0, op0);
    __builtin_nontemporal_store(o1, op1);
}

// ---------------------------------------------------------------------------
extern "C" void kernel_launch(void* const* d_in, const int* in_sizes, int n_in,
                              void* d_out, int out_size, void* d_ws, size_t ws_size,
                              hipStream_t stream)
{
    const float* x       = (const float*)d_in[0];
    const int*   ei      = (const int*)d_in[1];
    const float* W       = (const float*)d_in[2];
    const float* att_src = (const float*)d_in[3];
    const float* att_dst = (const float*)d_in[4];
    const float* bias    = (const float*)d_in[5];
    float* out = (float*)d_out;

    char* ws = (char*)d_ws;
    unsigned* hbu  = (unsigned*)(ws);              // 10,240,000 B (interleaved h)
    float*    as2  = (float*)(ws + 10240000);      //    160,000 B (float2[NN])
    float*    ad2  = (float*)(ws + 10400000);      //    160,000 B (float2[NN])
    int*      cnt4 = (int*)(ws + 10560000);        //    320,000 B (4 replicas)
    ushort*   buck = (ushort*)(ws + 10880000);     // 10,240,000 B (4*NN*64 ushort)

    gemm_att_kernel<<<(BB * NN) / 64, 256, 0, stream>>>(x, W, att_src, att_dst,
                                                        hbu, as2, ad2, cnt4);
    scatter_kernel<<<(EP + 1023) / 1024, 256, 0, stream>>>(ei, cnt4, buck);
    gather_kernel<<<NN / 4, 256, 0, stream>>>((const uint2*)hbu, cnt4, buck,
                                              (const float2*)as2,
                                              (const float2*)ad2, bias, out);
}

// Round 14
// 98.272 us; speedup vs baseline: 1.1132x; 1.1132x over previous
//
#include <hip/hip_runtime.h>
#include <hip/hip_bf16.h>
#include <math.h>

#define BB    2
#define NN    20000
#define FF    128
#define EE    640000
#define EP    (EE + NN)      // edges + self loops = 660000
#define NBIN  79             // ceil(NN/256) coarse bins of 256 nodes
#define BINCAP 10240         // words per bin (mean 8448, +19 sigma)
#define SLOPE 0.2f

typedef __attribute__((ext_vector_type(8))) short bf16x8;
typedef __attribute__((ext_vector_type(4))) float f32x4;

static __device__ __forceinline__ ushort f2bf(float f) {
    unsigned u = __float_as_uint(f);
    u += 0x7fffu + ((u >> 16) & 1u);     // round-to-nearest-even
    return (ushort)(u >> 16);
}
static __device__ __forceinline__ float bf2f(unsigned hw) {
    return __uint_as_float(hw << 16);
}
static __device__ __forceinline__ float bflo(unsigned q) {
    return __uint_as_float(q << 16);
}
static __device__ __forceinline__ float bfhi(unsigned q) {
    return __uint_as_float(q & 0xffff0000u);
}

// ---------------------------------------------------------------------------
// MFMA GEMM: h = bf16(x) @ bf16(W)^T, f32 accumulate.
// h stored batch-interleaved: hbu[n*128 + pair*2 + b] = bf16x2(h[b][n][2p..2p+1])
// Block: 256 thr (4 waves), tile 64 rows x 128 cols, K=128.
// LDS tiles XOR-swizzled (byte ^= (row&7)<<4) -> conflict-free ds_read_b128.
// ---------------------------------------------------------------------------
__global__ __launch_bounds__(256) void gemm_att_kernel(
    const float* __restrict__ x, const float* __restrict__ W,
    const float* __restrict__ att_src, const float* __restrict__ att_dst,
    unsigned* __restrict__ hbu, float* __restrict__ as2, float* __restrict__ ad2)
{
    __shared__ ushort XL[64 * 128];    // 16 KB swizzled bf16 x-tile
    __shared__ ushort WL[128 * 128];   // 32 KB swizzled bf16 W (row c, col k)
    const int tid = threadIdx.x;
    const int r0 = blockIdx.x * 64;

    // stage x tile: 64 rows x 128 f32 = 2048 float4
    {
        const float4* xg = (const float4*)(x + (size_t)r0 * 128);
        #pragma unroll
        for (int i = 0; i < 8; ++i) {
            int idx = tid + i * 256;          // float4 idx; 32 per row
            int r = idx >> 5, k = (idx & 31) * 4;
            float4 v = xg[idx];
            ushort4 p = { f2bf(v.x), f2bf(v.y), f2bf(v.z), f2bf(v.w) };
            unsigned byte = ((unsigned)r << 8) + ((unsigned)k << 1);
            byte ^= (unsigned)(r & 7) << 4;
            *(ushort4*)((char*)XL + byte) = p;
        }
    }
    // stage W: 128x128 f32 = 4096 float4
    {
        const float4* wg = (const float4*)W;
        #pragma unroll
        for (int i = 0; i < 16; ++i) {
            int idx = tid + i * 256;
            int c = idx >> 5, k = (idx & 31) * 4;
            float4 v = wg[idx];
            ushort4 p = { f2bf(v.x), f2bf(v.y), f2bf(v.z), f2bf(v.w) };
            unsigned byte = ((unsigned)c << 8) + ((unsigned)k << 1);
            byte ^= (unsigned)(c & 7) << 4;
            *(ushort4*)((char*)WL + byte) = p;
        }
    }
    __syncthreads();

    const int wid = tid >> 6, lane = tid & 63;
    const int l15 = lane & 15, lg = lane >> 4;
    f32x4 acc[8];
    #pragma unroll
    for (int i = 0; i < 8; ++i) acc[i] = (f32x4){0.f, 0.f, 0.f, 0.f};

    const int arow = wid * 16 + l15;
    #pragma unroll
    for (int kt = 0; kt < 4; ++kt) {
        unsigned abyte = ((unsigned)arow << 8) + (unsigned)(kt * 64 + lg * 16);
        abyte ^= (unsigned)(arow & 7) << 4;
        bf16x8 af = *(const bf16x8*)((const char*)XL + abyte);
        #pragma unroll
        for (int ct = 0; ct < 8; ++ct) {
            int c = ct * 16 + l15;
            unsigned bbyte = ((unsigned)c << 8) + (unsigned)(kt * 64 + lg * 16);
            bbyte ^= (unsigned)(c & 7) << 4;
            bf16x8 bfr = *(const bf16x8*)((const char*)WL + bbyte);
            acc[ct] = __builtin_amdgcn_mfma_f32_16x16x32_bf16(af, bfr, acc[ct], 0, 0, 0);
        }
    }

    // a_src/a_dst from f32 accumulators: row = wid*16 + lg*4 + reg, col = ct*16+l15
    float ps0=0,ps1=0,ps2=0,ps3=0, pd0=0,pd1=0,pd2=0,pd3=0;
    #pragma unroll
    for (int ct = 0; ct < 8; ++ct) {
        int c = ct * 16 + l15;
        float as_ = att_src[c], ad_ = att_dst[c];
        ps0 += acc[ct][0]*as_; pd0 += acc[ct][0]*ad_;
        ps1 += acc[ct][1]*as_; pd1 += acc[ct][1]*ad_;
        ps2 += acc[ct][2]*as_; pd2 += acc[ct][2]*ad_;
        ps3 += acc[ct][3]*as_; pd3 += acc[ct][3]*ad_;
    }
    #pragma unroll
    for (int o = 1; o < 16; o <<= 1) {
        ps0 += __shfl_xor(ps0, o, 64); pd0 += __shfl_xor(pd0, o, 64);
        ps1 += __shfl_xor(ps1, o, 64); pd1 += __shfl_xor(pd1, o, 64);
        ps2 += __shfl_xor(ps2, o, 64); pd2 += __shfl_xor(pd2, o, 64);
        ps3 += __shfl_xor(ps3, o, 64); pd3 += __shfl_xor(pd3, o, 64);
    }
    if (l15 == 0) {
        int rb = r0 + wid * 16 + lg * 4;     // multiple of 4; quads never cross NN
        #pragma unroll
        for (int q = 0; q < 4; ++q) {
            int r = rb + q;
            int b = (r >= NN);
            int n = r - b * NN;
            float ps = q==0?ps0 : q==1?ps1 : q==2?ps2 : ps3;
            float pd = q==0?pd0 : q==1?pd1 : q==2?pd2 : pd3;
            as2[n * 2 + b] = ps;             // batch-packed float2 halves
            ad2[n * 2 + b] = pd;
        }
    }

    // h epilogue: acc -> LDS bf16 (linear) -> batch-interleaved global write
    __syncthreads();
    ushort* hl = (ushort*)WL;          // reuse 16 KB of WL
    {
        int rb = wid * 16 + lg * 4;
        #pragma unroll
        for (int ct = 0; ct < 8; ++ct) {
            int c = ct * 16 + l15;
            hl[(rb+0) * 128 + c] = f2bf(acc[ct][0]);
            hl[(rb+1) * 128 + c] = f2bf(acc[ct][1]);
            hl[(rb+2) * 128 + c] = f2bf(acc[ct][2]);
            hl[(rb+3) * 128 + c] = f2bf(acc[ct][3]);
        }
    }
    __syncthreads();
    {
        const unsigned* hs = (const unsigned*)hl;   // 64 rows x 64 pairs
        #pragma unroll
        for (int i = 0; i < 16; ++i) {
            int idx = tid + i * 256;       // 0..4095
            int row = idx >> 6, p = idx & 63;
            int r = r0 + row;
            int b = (r >= NN);
            int n = r - b * NN;
            hbu[(size_t)n * 128 + p * 2 + b] = hs[row * 64 + p];
        }
    }
}

// ---------------------------------------------------------------------------
// Pass 1: bin edges by dst>>8 (79 bins). LDS histogram + local pack, ONE bulk
// global atomic per (block,bin), coalesced burst copy to bin segments.
// word = (d&255)<<15 | s   (s < 32768)
// ---------------------------------------------------------------------------
__global__ __launch_bounds__(256) void bin_kernel(
    const int* __restrict__ ei, int* __restrict__ binCur,
    unsigned* __restrict__ binbuf)
{
    __shared__ int hcnt[NBIN];
    __shared__ int hofs[NBIN + 1];
    __shared__ int hbase[NBIN];
    __shared__ int hcur[NBIN];
    __shared__ unsigned stage[1024];
    const int tid = threadIdx.x;
    for (int i = tid; i < NBIN; i += 256) hcnt[i] = 0;
    __syncthreads();

    const int e0 = blockIdx.x * 1024;
    int bin[4]; unsigned word[4];
    #pragma unroll
    for (int k = 0; k < 4; ++k) {
        int e = e0 + k * 256 + tid;
        bin[k] = -1;
        if (e < EP) {
            int s, d; bool ok;
            if (e < EE) {
                s = ei[e]; d = ei[EE + e];
                ok = ((unsigned)s < NN) && ((unsigned)d < NN);
            } else { s = d = e - EE; ok = true; }
            if (ok) {
                bin[k] = d >> 8;
                word[k] = ((unsigned)(d & 255) << 15) | (unsigned)s;
                atomicAdd(&hcnt[bin[k]], 1);
            }
        }
    }
    __syncthreads();
    if (tid == 0) {
        int run = 0;
        for (int b = 0; b < NBIN; ++b) { hofs[b] = run; run += hcnt[b]; }
        hofs[NBIN] = run;
    }
    __syncthreads();
    if (tid < NBIN) {
        hbase[tid] = atomicAdd(&binCur[tid], hcnt[tid]);
        hcur[tid] = 0;
    }
    __syncthreads();
    #pragma unroll
    for (int k = 0; k < 4; ++k) {
        if (bin[k] >= 0) {
            int slot = atomicAdd(&hcur[bin[k]], 1);
            stage[hofs[bin[k]] + slot] = word[k];
        }
    }
    __syncthreads();
    const int total = hofs[NBIN];
    for (int i = tid; i < total; i += 256) {
        int lo = 0, hi = NBIN;               // find b: hofs[b] <= i < hofs[b+1]
        while (hi - lo > 1) { int mid = (lo + hi) >> 1; if (hofs[mid] <= i) lo = mid; else hi = mid; }
        binbuf[(size_t)lo * BINCAP + hbase[lo] + (i - hofs[lo])] = stage[i];
    }
}

// ---------------------------------------------------------------------------
// Pass 2: per bin, build per-node CSR via LDS histogram+scan; compute bf16
// exp-weights (as2/ad2 L2-resident); write uint2 records scattered only
// within the bin's 80-KB L2-resident window. Emits nodeStart/nodeCnt.
// ---------------------------------------------------------------------------
__global__ __launch_bounds__(1024) void sort_kernel(
    const unsigned* __restrict__ binbuf, const int* __restrict__ binCur,
    const float2* __restrict__ as2, const float2* __restrict__ ad2,
    uint2* __restrict__ rec, int* __restrict__ nodeStart,
    int* __restrict__ nodeCnt)
{
    __shared__ int ncnt[256];
    __shared__ int nofs[256];
    __shared__ int ncur[256];
    const int b = blockIdx.x;
    const int tid = threadIdx.x;
    const int cnt = min(binCur[b], BINCAP);
    const unsigned* src = binbuf + (size_t)b * BINCAP;

    if (tid < 256) ncnt[tid] = 0;
    __syncthreads();
    for (int i = tid; i < cnt; i += 1024)
        atomicAdd(&ncnt[src[i] >> 15], 1);
    __syncthreads();
    if (tid == 0) {
        int run = 0;
        for (int i = 0; i < 256; ++i) { nofs[i] = run; run += ncnt[i]; }
    }
    __syncthreads();
    if (tid < 256) {
        int n = b * 256 + tid;
        if (n < NN) {
            nodeStart[n] = b * BINCAP + nofs[tid];
            nodeCnt[n]   = ncnt[tid];
        }
        ncur[tid] = 0;
    }
    __syncthreads();
    for (int i = tid; i < cnt; i += 1024) {
        unsigned w = src[i];
        int dl = w >> 15;
        int s  = w & 0x7fff;
        int d  = b * 256 + dl;
        float2 av = as2[s];
        float2 dv = ad2[d];
        float l0 = av.x + dv.x; l0 = l0 > 0.f ? l0 : SLOPE * l0;
        float l1 = av.y + dv.y; l1 = l1 > 0.f ? l1 : SLOPE * l1;
        int slot = atomicAdd(&ncur[dl], 1);
        uint2 r = { (unsigned)s | ((unsigned)f2bf(__expf(l0)) << 16),
                    (unsigned)f2bf(__expf(l1)) };
        rec[(size_t)b * BINCAP + nofs[dl] + slot] = r;
    }
}

// ---------------------------------------------------------------------------
// Gather: ONE WAVE per node (4 nodes per 256-thr block). No __syncthreads.
// Stage: 2 coalesced uint2 record loads (contiguous segment); den via shuffle.
// Inner loop: unroll x4 -> 4 h-loads (512 B each) in flight per wave.
// ---------------------------------------------------------------------------
__global__ __launch_bounds__(256) void gather_kernel(
    const uint2* __restrict__ h,             // [N][64] uint2 {b0 pair, b1 pair}
    const int* __restrict__ nodeStart, const int* __restrict__ nodeCnt,
    const uint2* __restrict__ rec,
    const float* __restrict__ bias, float* __restrict__ out)
{
    const int tid = threadIdx.x;
    const int wid = tid >> 6, lane = tid & 63;
    const int n = blockIdx.x * 4 + wid;

    __shared__ ushort ssrc[4][128];
    __shared__ float2 swp[4][128];

    const int beg = nodeStart[n];
    const int cn = min(nodeCnt[n], 128);

    float den0 = 0.f, den1 = 0.f;
    #pragma unroll
    for (int r = 0; r < 2; ++r) {
        int j = r * 64 + lane;
        if (j < cn) {
            uint2 rc = rec[(size_t)beg + j];
            float w0 = bf2f(rc.x >> 16);
            float w1 = bf2f(rc.y & 0xffffu);
            ssrc[wid][j] = (ushort)(rc.x & 0xffffu);
            swp[wid][j] = (float2){w0, w1};
            den0 += w0; den1 += w1;
        }
    }
    #pragma unroll
    for (int o = 32; o > 0; o >>= 1) {
        den0 += __shfl_xor(den0, o, 64);
        den1 += __shfl_xor(den1, o, 64);
    }

    float a0x = 0.f, a0y = 0.f, a1x = 0.f, a1y = 0.f;
    int j = 0;
    for (; j + 3 < cn; j += 4) {
        int s0 = ssrc[wid][j],     s1 = ssrc[wid][j + 1];
        int s2 = ssrc[wid][j + 2], s3 = ssrc[wid][j + 3];
        uint2 q0 = h[(size_t)s0 * 64 + lane];
        uint2 q1 = h[(size_t)s1 * 64 + lane];
        uint2 q2 = h[(size_t)s2 * 64 + lane];
        uint2 q3 = h[(size_t)s3 * 64 + lane];
        float2 w0 = swp[wid][j],     w1 = swp[wid][j + 1];
        float2 w2 = swp[wid][j + 2], w3 = swp[wid][j + 3];
        a0x += w0.x * bflo(q0.x); a0y += w0.x * bfhi(q0.x);
        a1x += w0.y * bflo(q0.y); a1y += w0.y * bfhi(q0.y);
        a0x += w1.x * bflo(q1.x); a0y += w1.x * bfhi(q1.x);
        a1x += w1.y * bflo(q1.y); a1y += w1.y * bfhi(q1.y);
        a0x += w2.x * bflo(q2.x); a0y += w2.x * bfhi(q2.x);
        a1x += w2.y * bflo(q2.y); a1y += w2.y * bfhi(q2.y);
        a0x += w3.x * bflo(q3.x); a0y += w3.x * bfhi(q3.x);
        a1x += w3.y * bflo(q3.y); a1y += w3.y * bfhi(q3.y);
    }
    for (; j < cn; ++j) {
        int s0 = ssrc[wid][j];
        uint2 q0 = h[(size_t)s0 * 64 + lane];
        float2 w0 = swp[wid][j];
        a0x += w0.x * bflo(q0.x); a0y += w0.x * bfhi(q0.x);
        a1x += w0.y * bflo(q0.y); a1y += w0.y * bfhi(q0.y);
    }

    float r0 = 1.f / den0, r1 = 1.f / den1;
    float2 bv = *(const float2*)&bias[lane * 2];
    float2 o0 = { a0x * r0 + bv.x, a0y * r0 + bv.y };
    float2 o1 = { a1x * r1 + bv.x, a1y * r1 + bv.y };
    *(float2*)&out[(size_t)n * 128 + lane * 2]        = o0;
    *(float2*)&out[((size_t)NN + n) * 128 + lane * 2] = o1;
}

// ---------------------------------------------------------------------------
extern "C" void kernel_launch(void* const* d_in, const int* in_sizes, int n_in,
                              void* d_out, int out_size, void* d_ws, size_t ws_size,
                              hipStream_t stream)
{
    const float* x       = (const float*)d_in[0];
    const int*   ei      = (const int*)d_in[1];
    const float* W       = (const float*)d_in[2];
    const float* att_src = (const float*)d_in[3];
    const float* att_dst = (const float*)d_in[4];
    const float* bias    = (const float*)d_in[5];
    float* out = (float*)d_out;

    char* ws = (char*)d_ws;
    unsigned* hbu      = (unsigned*)(ws);            // 10,240,000 B
    float*    as2      = (float*)(ws + 10240000);    //    160,000 B
    float*    ad2      = (float*)(ws + 10400000);    //    160,000 B
    int*      binCur   = (int*)(ws + 10560000);      //        512 B
    unsigned* binbuf   = (unsigned*)(ws + 10560512); //  3,235,840 B (79*10240*4)
    uint2*    rec      = (uint2*)(ws + 13796352);    //  6,471,680 B (79*10240*8)
    int*      nodeStart= (int*)(ws + 20268032);      //     80,000 B
    int*      nodeCnt  = (int*)(ws + 20348032);      //     80,000 B

    hipMemsetAsync(binCur, 0, NBIN * sizeof(int), stream);
    bin_kernel<<<(EP + 1023) / 1024, 256, 0, stream>>>(ei, binCur, binbuf);
    gemm_att_kernel<<<(BB * NN) / 64, 256, 0, stream>>>(x, W, att_src, att_dst,
                                                        hbu, as2, ad2);
    sort_kernel<<<NBIN, 1024, 0, stream>>>(binbuf, binCur,
                                           (const float2*)as2, (const float2*)ad2,
                                           rec, nodeStart, nodeCnt);
    gather_kernel<<<NN / 4, 256, 0, stream>>>((const uint2*)hbu, nodeStart,
                                              nodeCnt, rec, bias, out);
}

// Round 15
// 90.368 us; speedup vs baseline: 1.2106x; 1.0875x over previous
//
#include <hip/hip_runtime.h>
#include <hip/hip_bf16.h>
#include <math.h>

#define BB    2
#define NN    20000
#define FF    128
#define EE    640000
#define EP    (EE + NN)      // edges + self loops = 660000
#define NBIN  157            // ceil(NN/128) bins of 128 nodes
#define BINCAP 5120          // words per bin (mean 4204, +14 sigma)
#define SLOPE 0.2f

typedef __attribute__((ext_vector_type(8))) short bf16x8;
typedef __attribute__((ext_vector_type(4))) float f32x4;

static __device__ __forceinline__ ushort f2bf(float f) {
    unsigned u = __float_as_uint(f);
    u += 0x7fffu + ((u >> 16) & 1u);     // round-to-nearest-even
    return (ushort)(u >> 16);
}
static __device__ __forceinline__ float bf2f(unsigned hw) {
    return __uint_as_float(hw << 16);
}
static __device__ __forceinline__ float bflo(unsigned q) {
    return __uint_as_float(q << 16);
}
static __device__ __forceinline__ float bfhi(unsigned q) {
    return __uint_as_float(q & 0xffff0000u);
}

// ---------------------------------------------------------------------------
// MFMA GEMM: h = bf16(x) @ bf16(W)^T, f32 accumulate.
// h stored batch-interleaved: hbu[n*128 + pair*2 + b] = bf16x2(h[b][n][2p..2p+1])
// ---------------------------------------------------------------------------
__global__ __launch_bounds__(256) void gemm_att_kernel(
    const float* __restrict__ x, const float* __restrict__ W,
    const float* __restrict__ att_src, const float* __restrict__ att_dst,
    unsigned* __restrict__ hbu, float* __restrict__ as2, float* __restrict__ ad2)
{
    __shared__ ushort XL[64 * 128];    // 16 KB swizzled bf16 x-tile
    __shared__ ushort WL[128 * 128];   // 32 KB swizzled bf16 W (row c, col k)
    const int tid = threadIdx.x;
    const int r0 = blockIdx.x * 64;

    {
        const float4* xg = (const float4*)(x + (size_t)r0 * 128);
        #pragma unroll
        for (int i = 0; i < 8; ++i) {
            int idx = tid + i * 256;
            int r = idx >> 5, k = (idx & 31) * 4;
            float4 v = xg[idx];
            ushort4 p = { f2bf(v.x), f2bf(v.y), f2bf(v.z), f2bf(v.w) };
            unsigned byte = ((unsigned)r << 8) + ((unsigned)k << 1);
            byte ^= (unsigned)(r & 7) << 4;
            *(ushort4*)((char*)XL + byte) = p;
        }
    }
    {
        const float4* wg = (const float4*)W;
        #pragma unroll
        for (int i = 0; i < 16; ++i) {
            int idx = tid + i * 256;
            int c = idx >> 5, k = (idx & 31) * 4;
            float4 v = wg[idx];
            ushort4 p = { f2bf(v.x), f2bf(v.y), f2bf(v.z), f2bf(v.w) };
            unsigned byte = ((unsigned)c << 8) + ((unsigned)k << 1);
            byte ^= (unsigned)(c & 7) << 4;
            *(ushort4*)((char*)WL + byte) = p;
        }
    }
    __syncthreads();

    const int wid = tid >> 6, lane = tid & 63;
    const int l15 = lane & 15, lg = lane >> 4;
    f32x4 acc[8];
    #pragma unroll
    for (int i = 0; i < 8; ++i) acc[i] = (f32x4){0.f, 0.f, 0.f, 0.f};

    const int arow = wid * 16 + l15;
    #pragma unroll
    for (int kt = 0; kt < 4; ++kt) {
        unsigned abyte = ((unsigned)arow << 8) + (unsigned)(kt * 64 + lg * 16);
        abyte ^= (unsigned)(arow & 7) << 4;
        bf16x8 af = *(const bf16x8*)((const char*)XL + abyte);
        #pragma unroll
        for (int ct = 0; ct < 8; ++ct) {
            int c = ct * 16 + l15;
            unsigned bbyte = ((unsigned)c << 8) + (unsigned)(kt * 64 + lg * 16);
            bbyte ^= (unsigned)(c & 7) << 4;
            bf16x8 bfr = *(const bf16x8*)((const char*)WL + bbyte);
            acc[ct] = __builtin_amdgcn_mfma_f32_16x16x32_bf16(af, bfr, acc[ct], 0, 0, 0);
        }
    }

    float ps0=0,ps1=0,ps2=0,ps3=0, pd0=0,pd1=0,pd2=0,pd3=0;
    #pragma unroll
    for (int ct = 0; ct < 8; ++ct) {
        int c = ct * 16 + l15;
        float as_ = att_src[c], ad_ = att_dst[c];
        ps0 += acc[ct][0]*as_; pd0 += acc[ct][0]*ad_;
        ps1 += acc[ct][1]*as_; pd1 += acc[ct][1]*ad_;
        ps2 += acc[ct][2]*as_; pd2 += acc[ct][2]*ad_;
        ps3 += acc[ct][3]*as_; pd3 += acc[ct][3]*ad_;
    }
    #pragma unroll
    for (int o = 1; o < 16; o <<= 1) {
        ps0 += __shfl_xor(ps0, o, 64); pd0 += __shfl_xor(pd0, o, 64);
        ps1 += __shfl_xor(ps1, o, 64); pd1 += __shfl_xor(pd1, o, 64);
        ps2 += __shfl_xor(ps2, o, 64); pd2 += __shfl_xor(pd2, o, 64);
        ps3 += __shfl_xor(ps3, o, 64); pd3 += __shfl_xor(pd3, o, 64);
    }
    if (l15 == 0) {
        int rb = r0 + wid * 16 + lg * 4;
        #pragma unroll
        for (int q = 0; q < 4; ++q) {
            int r = rb + q;
            int b = (r >= NN);
            int n = r - b * NN;
            float ps = q==0?ps0 : q==1?ps1 : q==2?ps2 : ps3;
            float pd = q==0?pd0 : q==1?pd1 : q==2?pd2 : pd3;
            as2[n * 2 + b] = ps;
            ad2[n * 2 + b] = pd;
        }
    }

    __syncthreads();
    ushort* hl = (ushort*)WL;
    {
        int rb = wid * 16 + lg * 4;
        #pragma unroll
        for (int ct = 0; ct < 8; ++ct) {
            int c = ct * 16 + l15;
            hl[(rb+0) * 128 + c] = f2bf(acc[ct][0]);
            hl[(rb+1) * 128 + c] = f2bf(acc[ct][1]);
            hl[(rb+2) * 128 + c] = f2bf(acc[ct][2]);
            hl[(rb+3) * 128 + c] = f2bf(acc[ct][3]);
        }
    }
    __syncthreads();
    {
        const unsigned* hs = (const unsigned*)hl;
        #pragma unroll
        for (int i = 0; i < 16; ++i) {
            int idx = tid + i * 256;
            int row = idx >> 6, p = idx & 63;
            int r = r0 + row;
            int b = (r >= NN);
            int n = r - b * NN;
            hbu[(size_t)n * 128 + p * 2 + b] = hs[row * 64 + p];
        }
    }
}

// ---------------------------------------------------------------------------
// Pass 1: bin edges by dst>>7 (157 bins of 128 nodes). LDS histogram +
// parallel scan + local pack, ONE bulk global atomic per (block,bin),
// coalesced burst copy. word = (d&127)<<15 | s  (s < 32768)
// ---------------------------------------------------------------------------
__global__ __launch_bounds__(256) void bin_kernel(
    const int* __restrict__ ei, int* __restrict__ binCur,
    unsigned* __restrict__ binbuf)
{
    __shared__ int hcnt[NBIN];
    __shared__ int scan[256];
    __shared__ int hofs[NBIN + 1];
    __shared__ int hbase[NBIN];
    __shared__ int hcur[NBIN];
    __shared__ unsigned stage[1024];
    const int tid = threadIdx.x;
    for (int i = tid; i < NBIN; i += 256) { hcnt[i] = 0; hcur[i] = 0; }
    __syncthreads();

    const int e0 = blockIdx.x * 1024;
    int bin[4]; unsigned word[4];
    #pragma unroll
    for (int k = 0; k < 4; ++k) {
        int e = e0 + k * 256 + tid;
        bin[k] = -1;
        if (e < EP) {
            int s, d; bool ok;
            if (e < EE) {
                s = ei[e]; d = ei[EE + e];
                ok = ((unsigned)s < NN) && ((unsigned)d < NN);
            } else { s = d = e - EE; ok = true; }
            if (ok) {
                bin[k] = d >> 7;
                word[k] = ((unsigned)(d & 127) << 15) | (unsigned)s;
                atomicAdd(&hcnt[bin[k]], 1);
            }
        }
    }
    __syncthreads();
    // parallel inclusive scan over NBIN (padded to 256)
    scan[tid] = (tid < NBIN) ? hcnt[tid] : 0;
    __syncthreads();
    #pragma unroll
    for (int o = 1; o < 256; o <<= 1) {
        int v = (tid >= o) ? scan[tid - o] : 0;
        __syncthreads();
        scan[tid] += v;
        __syncthreads();
    }
    if (tid < NBIN) hofs[tid] = scan[tid] - hcnt[tid];   // exclusive
    if (tid == 0) hofs[NBIN] = 0;                        // placeholder
    __syncthreads();
    if (tid == 0) hofs[NBIN] = scan[NBIN - 1];           // total
    if (tid < NBIN) hbase[tid] = atomicAdd(&binCur[tid], hcnt[tid]);
    __syncthreads();
    #pragma unroll
    for (int k = 0; k < 4; ++k) {
        if (bin[k] >= 0) {
            int slot = atomicAdd(&hcur[bin[k]], 1);
            stage[hofs[bin[k]] + slot] = word[k];
        }
    }
    __syncthreads();
    const int total = hofs[NBIN];
    for (int i = tid; i < total; i += 256) {
        int lo = 0, hi = NBIN;               // find b: hofs[b] <= i < hofs[b+1]
        while (hi - lo > 1) { int mid = (lo + hi) >> 1; if (hofs[mid] <= i) lo = mid; else hi = mid; }
        int slot = hbase[lo] + (i - hofs[lo]);
        if (slot < BINCAP)
            binbuf[(size_t)lo * BINCAP + slot] = stage[i];
    }
}

// ---------------------------------------------------------------------------
// Pass 2: per bin (128 nodes), LDS histogram + parallel scan -> local CSR;
// bf16 exp-weights (as2/ad2 L2-resident); records land in the bin's 40-KB
// L2-resident window. Emits nodeStart/nodeCnt.
// ---------------------------------------------------------------------------
__global__ __launch_bounds__(1024) void sort_kernel(
    const unsigned* __restrict__ binbuf, const int* __restrict__ binCur,
    const float2* __restrict__ as2, const float2* __restrict__ ad2,
    uint2* __restrict__ rec, int* __restrict__ nodeStart,
    int* __restrict__ nodeCnt)
{
    __shared__ int ncnt[128];
    __shared__ int scan[128];
    __shared__ int nofs[128];
    __shared__ int ncur[128];
    const int b = blockIdx.x;
    const int tid = threadIdx.x;
    const int cnt = min(binCur[b], BINCAP);
    const unsigned* src = binbuf + (size_t)b * BINCAP;

    if (tid < 128) { ncnt[tid] = 0; ncur[tid] = 0; }
    __syncthreads();
    for (int i = tid; i < cnt; i += 1024)
        atomicAdd(&ncnt[src[i] >> 15], 1);
    __syncthreads();
    // parallel inclusive scan over 128 node counts
    if (tid < 128) scan[tid] = ncnt[tid];
    __syncthreads();
    #pragma unroll
    for (int o = 1; o < 128; o <<= 1) {
        int v = 0;
        if (tid < 128 && tid >= o) v = scan[tid - o];
        __syncthreads();
        if (tid < 128) scan[tid] += v;
        __syncthreads();
    }
    if (tid < 128) {
        nofs[tid] = scan[tid] - ncnt[tid];
        int n = b * 128 + tid;
        if (n < NN) {
            nodeStart[n] = b * BINCAP + nofs[tid];
            nodeCnt[n]   = ncnt[tid];
        }
    }
    __syncthreads();
    for (int i = tid; i < cnt; i += 1024) {
        unsigned w = src[i];
        int dl = w >> 15;
        int s  = w & 0x7fff;
        int d  = b * 128 + dl;
        float2 av = as2[s];
        float2 dv = ad2[d];
        float l0 = av.x + dv.x; l0 = l0 > 0.f ? l0 : SLOPE * l0;
        float l1 = av.y + dv.y; l1 = l1 > 0.f ? l1 : SLOPE * l1;
        int slot = atomicAdd(&ncur[dl], 1);
        uint2 r = { (unsigned)s | ((unsigned)f2bf(__expf(l0)) << 16),
                    (unsigned)f2bf(__expf(l1)) };
        rec[(size_t)b * BINCAP + nofs[dl] + slot] = r;
    }
}

// ---------------------------------------------------------------------------
// Gather: ONE WAVE per node (4 nodes per 256-thr block). No __syncthreads.
// ---------------------------------------------------------------------------
__global__ __launch_bounds__(256) void gather_kernel(
    const uint2* __restrict__ h,             // [N][64] uint2 {b0 pair, b1 pair}
    const int* __restrict__ nodeStart, const int* __restrict__ nodeCnt,
    const uint2* __restrict__ rec,
    const float* __restrict__ bias, float* __restrict__ out)
{
    const int tid = threadIdx.x;
    const int wid = tid >> 6, lane = tid & 63;
    const int n = blockIdx.x * 4 + wid;

    __shared__ ushort ssrc[4][128];
    __shared__ float2 swp[4][128];

    const int beg = nodeStart[n];
    const int cn = min(nodeCnt[n], 128);

    float den0 = 0.f, den1 = 0.f;
    #pragma unroll
    for (int r = 0; r < 2; ++r) {
        int j = r * 64 + lane;
        if (j < cn) {
            uint2 rc = rec[(size_t)beg + j];
            float w0 = bf2f(rc.x >> 16);
            float w1 = bf2f(rc.y & 0xffffu);
            ssrc[wid][j] = (ushort)(rc.x & 0xffffu);
            swp[wid][j] = (float2){w0, w1};
            den0 += w0; den1 += w1;
        }
    }
    #pragma unroll
    for (int o = 32; o > 0; o >>= 1) {
        den0 += __shfl_xor(den0, o, 64);
        den1 += __shfl_xor(den1, o, 64);
    }

    float a0x = 0.f, a0y = 0.f, a1x = 0.f, a1y = 0.f;
    int j = 0;
    for (; j + 3 < cn; j += 4) {
        int s0 = ssrc[wid][j],     s1 = ssrc[wid][j + 1];
        int s2 = ssrc[wid][j + 2], s3 = ssrc[wid][j + 3];
        uint2 q0 = h[(size_t)s0 * 64 + lane];
        uint2 q1 = h[(size_t)s1 * 64 + lane];
        uint2 q2 = h[(size_t)s2 * 64 + lane];
        uint2 q3 = h[(size_t)s3 * 64 + lane];
        float2 w0 = swp[wid][j],     w1 = swp[wid][j + 1];
        float2 w2 = swp[wid][j + 2], w3 = swp[wid][j + 3];
        a0x += w0.x * bflo(q0.x); a0y += w0.x * bfhi(q0.x);
        a1x += w0.y * bflo(q0.y); a1y += w0.y * bfhi(q0.y);
        a0x += w1.x * bflo(q1.x); a0y += w1.x * bfhi(q1.x);
        a1x += w1.y * bflo(q1.y); a1y += w1.y * bfhi(q1.y);
        a0x += w2.x * bflo(q2.x); a0y += w2.x * bfhi(q2.x);
        a1x += w2.y * bflo(q2.y); a1y += w2.y * bfhi(q2.y);
        a0x += w3.x * bflo(q3.x); a0y += w3.x * bfhi(q3.x);
        a1x += w3.y * bflo(q3.y); a1y += w3.y * bfhi(q3.y);
    }
    for (; j < cn; ++j) {
        int s0 = ssrc[wid][j];
        uint2 q0 = h[(size_t)s0 * 64 + lane];
        float2 w0 = swp[wid][j];
        a0x += w0.x * bflo(q0.x); a0y += w0.x * bfhi(q0.x);
        a1x += w0.y * bflo(q0.y); a1y += w0.y * bfhi(q0.y);
    }

    float r0 = 1.f / den0, r1 = 1.f / den1;
    float2 bv = *(const float2*)&bias[lane * 2];
    float2 o0 = { a0x * r0 + bv.x, a0y * r0 + bv.y };
    float2 o1 = { a1x * r1 + bv.x, a1y * r1 + bv.y };
    *(float2*)&out[(size_t)n * 128 + lane * 2]        = o0;
    *(float2*)&out[((size_t)NN + n) * 128 + lane * 2] = o1;
}

// ---------------------------------------------------------------------------
extern "C" void kernel_launch(void* const* d_in, const int* in_sizes, int n_in,
                              void* d_out, int out_size, void* d_ws, size_t ws_size,
                              hipStream_t stream)
{
    const float* x       = (const float*)d_in[0];
    const int*   ei      = (const int*)d_in[1];
    const float* W       = (const float*)d_in[2];
    const float* att_src = (const float*)d_in[3];
    const float* att_dst = (const float*)d_in[4];
    const float* bias    = (const float*)d_in[5];
    float* out = (float*)d_out;

    char* ws = (char*)d_ws;
    unsigned* hbu      = (unsigned*)(ws);            // 10,240,000 B
    float*    as2      = (float*)(ws + 10240000);    //    160,000 B
    float*    ad2      = (float*)(ws + 10400000);    //    160,000 B
    int*      binCur   = (int*)(ws + 10560000);      //      1,024 B
    unsigned* binbuf   = (unsigned*)(ws + 10561024); //  3,215,360 B (157*5120*4)
    uint2*    rec      = (uint2*)(ws + 13776384);    //  6,430,720 B (157*5120*8)
    int*      nodeStart= (int*)(ws + 20207104);      //     80,000 B
    int*      nodeCnt  = (int*)(ws + 20287104);      //     80,000 B

    hipMemsetAsync(binCur, 0, NBIN * sizeof(int), stream);
    bin_kernel<<<(EP + 1023) / 1024, 256, 0, stream>>>(ei, binCur, binbuf);
    gemm_att_kernel<<<(BB * NN) / 64, 256, 0, stream>>>(x, W, att_src, att_dst,
                                                        hbu, as2, ad2);
    sort_kernel<<<NBIN, 1024, 0, stream>>>(binbuf, binCur,
                                           (const float2*)as2, (const float2*)ad2,
                                           rec, nodeStart, nodeCnt);
    gather_kernel<<<NN / 4, 256, 0, stream>>>((const uint2*)hbu, nodeStart,
                                              nodeCnt, rec, bias, out);
}

// Round 16
// 79.598 us; speedup vs baseline: 1.3744x; 1.1353x over previous
//
#include <hip/hip_runtime.h>
#include <hip/hip_bf16.h>
#include <math.h>

#define BB    2
#define NN    20000
#define FF    128
#define EE    640000          // random edges (self-loops injected in sort)
#define NBIN  157             // ceil(NN/128) bins of 128 nodes
#define NBLK  625             // EE / 1024 edge blocks
#define SEGW  32              // words per (block,bin) segment; Poisson(6.5)
#define BSLOTS (NBLK * SEGW)  // 20000 slots per bin
#define RECCAP 5120           // rec entries per bin (mean 4208, +13 sigma)
#define GEMM_BLOCKS 625
#define SLOPE 0.2f

typedef __attribute__((ext_vector_type(8))) short bf16x8;
typedef __attribute__((ext_vector_type(4))) float f32x4;

static __device__ __forceinline__ ushort f2bf(float f) {
    unsigned u = __float_as_uint(f);
    u += 0x7fffu + ((u >> 16) & 1u);     // round-to-nearest-even
    return (ushort)(u >> 16);
}
static __device__ __forceinline__ float bf2f(unsigned hw) {
    return __uint_as_float(hw << 16);
}
static __device__ __forceinline__ float bflo(unsigned q) {
    return __uint_as_float(q << 16);
}
static __device__ __forceinline__ float bfhi(unsigned q) {
    return __uint_as_float(q & 0xffff0000u);
}

// ---------------------------------------------------------------------------
// Fused kernel. Blocks [0,625): MFMA GEMM h = bf16(x)@bf16(W)^T + a_src/a_dst.
// Blocks [625,1250): edge binning into per-(block,bin) fixed regions —
// NO global atomics, no memset dependency; LDS-only coordination.
// ---------------------------------------------------------------------------
__global__ __launch_bounds__(256) void fused_kernel(
    const float* __restrict__ x, const float* __restrict__ W,
    const float* __restrict__ att_src, const float* __restrict__ att_dst,
    const int* __restrict__ ei,
    unsigned* __restrict__ hbu, float* __restrict__ as2, float* __restrict__ ad2,
    ushort* __restrict__ cnts, unsigned* __restrict__ binbuf)
{
    __shared__ ushort XL[64 * 128];    // gemm: 16 KB x-tile | bin: int arrays
    __shared__ ushort WL[128 * 128];   // gemm: 32 KB W      | bin: stage words
    const int tid = threadIdx.x;

    if (blockIdx.x >= GEMM_BLOCKS) {
        // ---------------- bin part ----------------
        const int b2 = blockIdx.x - GEMM_BLOCKS;
        const int e0 = b2 * 1024;
        int* hcnt = (int*)XL;             // [157]
        int* hofs = hcnt + 160;           // [158]
        int* hcur = hofs + 160;           // [157]
        int* scan = hcur + 160;           // [256]
        unsigned* stage = (unsigned*)WL;  // [1024]

        for (int i = tid; i < NBIN; i += 256) { hcnt[i] = 0; hcur[i] = 0; }
        __syncthreads();

        int bin[4]; unsigned word[4];
        #pragma unroll
        for (int k = 0; k < 4; ++k) {
            int e = e0 + k * 256 + tid;   // always < EE
            int s = ei[e], d = ei[EE + e];
            bool ok = ((unsigned)s < NN) && ((unsigned)d < NN);
            bin[k] = ok ? (d >> 7) : -1;
            word[k] = ((unsigned)(d & 127) << 15) | (unsigned)(s & 0x7fff);
            if (ok) atomicAdd(&hcnt[bin[k]], 1);
        }
        __syncthreads();
        scan[tid] = (tid < NBIN) ? hcnt[tid] : 0;
        __syncthreads();
        #pragma unroll
        for (int o = 1; o < 256; o <<= 1) {
            int v = (tid >= o) ? scan[tid - o] : 0;
            __syncthreads();
            scan[tid] += v;
            __syncthreads();
        }
        if (tid < NBIN) hofs[tid] = scan[tid] - hcnt[tid];   // exclusive
        if (tid == 0) hofs[NBIN] = scan[NBIN - 1];
        if (tid < NBIN) cnts[b2 * NBIN + tid] = (ushort)min(hcnt[tid], SEGW);
        __syncthreads();
        #pragma unroll
        for (int k = 0; k < 4; ++k) {
            if (bin[k] >= 0) {
                int slot = atomicAdd(&hcur[bin[k]], 1);
                stage[hofs[bin[k]] + slot] = word[k];
            }
        }
        __syncthreads();
        const int total = hofs[NBIN];
        for (int i = tid; i < total; i += 256) {
            int lo = 0, hi = NBIN;
            while (hi - lo > 1) { int mid = (lo + hi) >> 1; if (hofs[mid] <= i) lo = mid; else hi = mid; }
            int j = i - hofs[lo];
            if (j < SEGW)
                binbuf[(size_t)lo * BSLOTS + b2 * SEGW + j] = stage[i];
        }
        return;
    }

    // ---------------- GEMM part ----------------
    const int r0 = blockIdx.x * 64;
    {
        const float4* xg = (const float4*)(x + (size_t)r0 * 128);
        #pragma unroll
        for (int i = 0; i < 8; ++i) {
            int idx = tid + i * 256;
            int r = idx >> 5, k = (idx & 31) * 4;
            float4 v = xg[idx];
            ushort4 p = { f2bf(v.x), f2bf(v.y), f2bf(v.z), f2bf(v.w) };
            unsigned byte = ((unsigned)r << 8) + ((unsigned)k << 1);
            byte ^= (unsigned)(r & 7) << 4;
            *(ushort4*)((char*)XL + byte) = p;
        }
    }
    {
        const float4* wg = (const float4*)W;
        #pragma unroll
        for (int i = 0; i < 16; ++i) {
            int idx = tid + i * 256;
            int c = idx >> 5, k = (idx & 31) * 4;
            float4 v = wg[idx];
            ushort4 p = { f2bf(v.x), f2bf(v.y), f2bf(v.z), f2bf(v.w) };
            unsigned byte = ((unsigned)c << 8) + ((unsigned)k << 1);
            byte ^= (unsigned)(c & 7) << 4;
            *(ushort4*)((char*)WL + byte) = p;
        }
    }
    __syncthreads();

    const int wid = tid >> 6, lane = tid & 63;
    const int l15 = lane & 15, lg = lane >> 4;
    f32x4 acc[8];
    #pragma unroll
    for (int i = 0; i < 8; ++i) acc[i] = (f32x4){0.f, 0.f, 0.f, 0.f};

    const int arow = wid * 16 + l15;
    #pragma unroll
    for (int kt = 0; kt < 4; ++kt) {
        unsigned abyte = ((unsigned)arow << 8) + (unsigned)(kt * 64 + lg * 16);
        abyte ^= (unsigned)(arow & 7) << 4;
        bf16x8 af = *(const bf16x8*)((const char*)XL + abyte);
        #pragma unroll
        for (int ct = 0; ct < 8; ++ct) {
            int c = ct * 16 + l15;
            unsigned bbyte = ((unsigned)c << 8) + (unsigned)(kt * 64 + lg * 16);
            bbyte ^= (unsigned)(c & 7) << 4;
            bf16x8 bfr = *(const bf16x8*)((const char*)WL + bbyte);
            acc[ct] = __builtin_amdgcn_mfma_f32_16x16x32_bf16(af, bfr, acc[ct], 0, 0, 0);
        }
    }

    float ps0=0,ps1=0,ps2=0,ps3=0, pd0=0,pd1=0,pd2=0,pd3=0;
    #pragma unroll
    for (int ct = 0; ct < 8; ++ct) {
        int c = ct * 16 + l15;
        float as_ = att_src[c], ad_ = att_dst[c];
        ps0 += acc[ct][0]*as_; pd0 += acc[ct][0]*ad_;
        ps1 += acc[ct][1]*as_; pd1 += acc[ct][1]*ad_;
        ps2 += acc[ct][2]*as_; pd2 += acc[ct][2]*ad_;
        ps3 += acc[ct][3]*as_; pd3 += acc[ct][3]*ad_;
    }
    #pragma unroll
    for (int o = 1; o < 16; o <<= 1) {
        ps0 += __shfl_xor(ps0, o, 64); pd0 += __shfl_xor(pd0, o, 64);
        ps1 += __shfl_xor(ps1, o, 64); pd1 += __shfl_xor(pd1, o, 64);
        ps2 += __shfl_xor(ps2, o, 64); pd2 += __shfl_xor(pd2, o, 64);
        ps3 += __shfl_xor(ps3, o, 64); pd3 += __shfl_xor(pd3, o, 64);
    }
    if (l15 == 0) {
        int rb = r0 + wid * 16 + lg * 4;
        #pragma unroll
        for (int q = 0; q < 4; ++q) {
            int r = rb + q;
            int b = (r >= NN);
            int n = r - b * NN;
            float ps = q==0?ps0 : q==1?ps1 : q==2?ps2 : ps3;
            float pd = q==0?pd0 : q==1?pd1 : q==2?pd2 : pd3;
            as2[n * 2 + b] = ps;
            ad2[n * 2 + b] = pd;
        }
    }

    __syncthreads();
    ushort* hl = (ushort*)WL;
    {
        int rb = wid * 16 + lg * 4;
        #pragma unroll
        for (int ct = 0; ct < 8; ++ct) {
            int c = ct * 16 + l15;
            hl[(rb+0) * 128 + c] = f2bf(acc[ct][0]);
            hl[(rb+1) * 128 + c] = f2bf(acc[ct][1]);
            hl[(rb+2) * 128 + c] = f2bf(acc[ct][2]);
            hl[(rb+3) * 128 + c] = f2bf(acc[ct][3]);
        }
    }
    __syncthreads();
    {
        const unsigned* hs = (const unsigned*)hl;
        #pragma unroll
        for (int i = 0; i < 16; ++i) {
            int idx = tid + i * 256;
            int row = idx >> 6, p = idx & 63;
            int r = r0 + row;
            int b = (r >= NN);
            int n = r - b * NN;
            hbu[(size_t)n * 128 + p * 2 + b] = hs[row * 64 + p];
        }
    }
}

// ---------------------------------------------------------------------------
// Sort: per bin (128 nodes), compact the 625 fixed segments, build per-node
// CSR (self-loop injected at slot 0), bf16 exp-weights, write rec in the
// bin's 40-KB L2-resident window. Emits nodeStart/nodeCnt.
// ---------------------------------------------------------------------------
__global__ __launch_bounds__(1024) void sort_kernel(
    const ushort* __restrict__ cnts, const unsigned* __restrict__ binbuf,
    const float2* __restrict__ as2, const float2* __restrict__ ad2,
    uint2* __restrict__ rec, int* __restrict__ nodeStart,
    int* __restrict__ nodeCnt)
{
    __shared__ ushort cb[NBLK];
    __shared__ int ncnt[128];
    __shared__ int scan[128];
    __shared__ int nofs[128];
    __shared__ int ncur[128];
    const int b = blockIdx.x;
    const int tid = threadIdx.x;
    const unsigned* src = binbuf + (size_t)b * BSLOTS;

    for (int i = tid; i < NBLK; i += 1024) cb[i] = cnts[i * NBIN + b];
    if (tid < 128) {
        int n = b * 128 + tid;
        int self = (n < NN) ? 1 : 0;
        ncnt[tid] = self;            // self-loop seed
        ncur[tid] = self;
    }
    __syncthreads();
    // histogram over valid slots
    for (int idx = tid; idx < BSLOTS; idx += 1024) {
        if ((idx & (SEGW - 1)) < cb[idx >> 5])
            atomicAdd(&ncnt[src[idx] >> 15], 1);
    }
    __syncthreads();
    if (tid < 128) scan[tid] = ncnt[tid];
    __syncthreads();
    #pragma unroll
    for (int o = 1; o < 128; o <<= 1) {
        int v = 0;
        if (tid < 128 && tid >= o) v = scan[tid - o];
        __syncthreads();
        if (tid < 128) scan[tid] += v;
        __syncthreads();
    }
    if (tid < 128) {
        nofs[tid] = scan[tid] - ncnt[tid];
        int n = b * 128 + tid;
        if (n < NN) {
            nodeStart[n] = b * RECCAP + nofs[tid];
            nodeCnt[n]   = ncnt[tid];
            // self-loop record at slot 0
            float2 av = as2[n];
            float2 dv = ad2[n];
            float l0 = av.x + dv.x; l0 = l0 > 0.f ? l0 : SLOPE * l0;
            float l1 = av.y + dv.y; l1 = l1 > 0.f ? l1 : SLOPE * l1;
            int pos = nofs[tid];
            if (pos < RECCAP) {
                uint2 r = { (unsigned)n | ((unsigned)f2bf(__expf(l0)) << 16),
                            (unsigned)f2bf(__expf(l1)) };
                rec[(size_t)b * RECCAP + pos] = r;
            }
        }
    }
    __syncthreads();
    for (int idx = tid; idx < BSLOTS; idx += 1024) {
        if ((idx & (SEGW - 1)) < cb[idx >> 5]) {
            unsigned w = src[idx];
            int dl = w >> 15;
            int s  = w & 0x7fff;
            int d  = b * 128 + dl;
            float2 av = as2[s];
            float2 dv = ad2[d];
            float l0 = av.x + dv.x; l0 = l0 > 0.f ? l0 : SLOPE * l0;
            float l1 = av.y + dv.y; l1 = l1 > 0.f ? l1 : SLOPE * l1;
            int slot = atomicAdd(&ncur[dl], 1);
            int pos = nofs[dl] + slot;
            if (pos < RECCAP) {
                uint2 r = { (unsigned)s | ((unsigned)f2bf(__expf(l0)) << 16),
                            (unsigned)f2bf(__expf(l1)) };
                rec[(size_t)b * RECCAP + pos] = r;
            }
        }
    }
}

// ---------------------------------------------------------------------------
// Gather: ONE WAVE per node (4 nodes per 256-thr block). No __syncthreads.
// ---------------------------------------------------------------------------
__global__ __launch_bounds__(256) void gather_kernel(
    const uint2* __restrict__ h,             // [N][64] uint2 {b0 pair, b1 pair}
    const int* __restrict__ nodeStart, const int* __restrict__ nodeCnt,
    const uint2* __restrict__ rec,
    const float* __restrict__ bias, float* __restrict__ out)
{
    const int tid = threadIdx.x;
    const int wid = tid >> 6, lane = tid & 63;
    const int n = blockIdx.x * 4 + wid;

    __shared__ ushort ssrc[4][128];
    __shared__ float2 swp[4][128];

    const int beg = nodeStart[n];
    const int cn = min(nodeCnt[n], 128);

    float den0 = 0.f, den1 = 0.f;
    #pragma unroll
    for (int r = 0; r < 2; ++r) {
        int j = r * 64 + lane;
        if (j < cn) {
            uint2 rc = rec[(size_t)beg + j];
            float w0 = bf2f(rc.x >> 16);
            float w1 = bf2f(rc.y & 0xffffu);
            ssrc[wid][j] = (ushort)(rc.x & 0xffffu);
            swp[wid][j] = (float2){w0, w1};
            den0 += w0; den1 += w1;
        }
    }
    #pragma unroll
    for (int o = 32; o > 0; o >>= 1) {
        den0 += __shfl_xor(den0, o, 64);
        den1 += __shfl_xor(den1, o, 64);
    }

    float a0x = 0.f, a0y = 0.f, a1x = 0.f, a1y = 0.f;
    int j = 0;
    for (; j + 3 < cn; j += 4) {
        int s0 = ssrc[wid][j],     s1 = ssrc[wid][j + 1];
        int s2 = ssrc[wid][j + 2], s3 = ssrc[wid][j + 3];
        uint2 q0 = h[(size_t)s0 * 64 + lane];
        uint2 q1 = h[(size_t)s1 * 64 + lane];
        uint2 q2 = h[(size_t)s2 * 64 + lane];
        uint2 q3 = h[(size_t)s3 * 64 + lane];
        float2 w0 = swp[wid][j],     w1 = swp[wid][j + 1];
        float2 w2 = swp[wid][j + 2], w3 = swp[wid][j + 3];
        a0x += w0.x * bflo(q0.x); a0y += w0.x * bfhi(q0.x);
        a1x += w0.y * bflo(q0.y); a1y += w0.y * bfhi(q0.y);
        a0x += w1.x * bflo(q1.x); a0y += w1.x * bfhi(q1.x);
        a1x += w1.y * bflo(q1.y); a1y += w1.y * bfhi(q1.y);
        a0x += w2.x * bflo(q2.x); a0y += w2.x * bfhi(q2.x);
        a1x += w2.y * bflo(q2.y); a1y += w2.y * bfhi(q2.y);
        a0x += w3.x * bflo(q3.x); a0y += w3.x * bfhi(q3.x);
        a1x += w3.y * bflo(q3.y); a1y += w3.y * bfhi(q3.y);
    }
    for (; j < cn; ++j) {
        int s0 = ssrc[wid][j];
        uint2 q0 = h[(size_t)s0 * 64 + lane];
        float2 w0 = swp[wid][j];
        a0x += w0.x * bflo(q0.x); a0y += w0.x * bfhi(q0.x);
        a1x += w0.y * bflo(q0.y); a1y += w0.y * bfhi(q0.y);
    }

    float r0 = 1.f / den0, r1 = 1.f / den1;
    float2 bv = *(const float2*)&bias[lane * 2];
    float2 o0 = { a0x * r0 + bv.x, a0y * r0 + bv.y };
    float2 o1 = { a1x * r1 + bv.x, a1y * r1 + bv.y };
    *(float2*)&out[(size_t)n * 128 + lane * 2]        = o0;
    *(float2*)&out[((size_t)NN + n) * 128 + lane * 2] = o1;
}

// ---------------------------------------------------------------------------
extern "C" void kernel_launch(void* const* d_in, const int* in_sizes, int n_in,
                              void* d_out, int out_size, void* d_ws, size_t ws_size,
                              hipStream_t stream)
{
    const float* x       = (const float*)d_in[0];
    const int*   ei      = (const int*)d_in[1];
    const float* W       = (const float*)d_in[2];
    const float* att_src = (const float*)d_in[3];
    const float* att_dst = (const float*)d_in[4];
    const float* bias    = (const float*)d_in[5];
    float* out = (float*)d_out;

    char* ws = (char*)d_ws;
    unsigned* hbu      = (unsigned*)(ws);            // 10,240,000 B
    float*    as2      = (float*)(ws + 10240000);    //    160,000 B
    float*    ad2      = (float*)(ws + 10400000);    //    160,000 B
    ushort*   cnts     = (ushort*)(ws + 10560000);   //    196,352 B (625*157 u16)
    unsigned* binbuf   = (unsigned*)(ws + 10756352); // 12,560,000 B (157*20000*4)
    uint2*    rec      = (uint2*)(ws + 23316352);    //  6,430,720 B (157*5120*8)
    int*      nodeStart= (int*)(ws + 29747072);      //     80,000 B
    int*      nodeCnt  = (int*)(ws + 29827072);      //     80,000 B

    fused_kernel<<<GEMM_BLOCKS + NBLK, 256, 0, stream>>>(
        x, W, att_src, att_dst, ei, hbu, as2, ad2, cnts, binbuf);
    sort_kernel<<<NBIN, 1024, 0, stream>>>(cnts, binbuf,
                                           (const float2*)as2, (const float2*)ad2,
                                           rec, nodeStart, nodeCnt);
    gather_kernel<<<NN / 4, 256, 0, stream>>>((const uint2*)hbu, nodeStart,
                                              nodeCnt, rec, bias, out);
}